// Round 8
// baseline (130.430 us; speedup 1.0000x reference)
//
#include <hip/hip_runtime.h>
#include <math.h>

#define BB 2
#define II 128
#define JJ 512
#define CC 256
#define NEL (BB*II*JJ)   // 131072
#define NINF (-INFINITY)
#define K10 4.5399929762484854e-5f   // exp(-10)

typedef float f32x4 __attribute__((ext_vector_type(4)));   // asm-operand-safe vec4

// ---------------- DPP wave64 primitives ----------------
template<int CTRL, int RM = 0xf, int BM = 0xf, bool BC = true>
__device__ __forceinline__ float dppf(float x) {
    return __int_as_float(__builtin_amdgcn_update_dpp(
        0, __float_as_int(x), CTRL, RM, BM, BC));
}
__device__ __forceinline__ float wscan_incl(float x) {
    x += dppf<0x111>(x);              // row_shr:1
    x += dppf<0x112>(x);              // row_shr:2
    x += dppf<0x114>(x);              // row_shr:4
    x += dppf<0x118>(x);              // row_shr:8
    x += dppf<0x142, 0xa>(x);         // row_bcast:15 -> rows 1,3
    x += dppf<0x143, 0xc>(x);         // row_bcast:31 -> rows 2,3
    return x;
}
__device__ __forceinline__ float lane_shr1(float x) { return dppf<0x138>(x); }
__device__ __forceinline__ float bcast63(float x) {
    return __int_as_float(__builtin_amdgcn_readlane(__float_as_int(x), 63));
}

// in-lane inclusive prefix sum, tree form (depth 3)
__device__ __forceinline__ void tree_prefix8(const float x[8], float P[8]) {
    float t[8];
    t[0] = x[0];
    #pragma unroll
    for (int q = 1; q < 8; ++q) t[q] = x[q] + x[q-1];
    float u[8];
    u[0] = t[0]; u[1] = t[1];
    #pragma unroll
    for (int q = 2; q < 8; ++q) u[q] = t[q] + t[q-2];
    P[0] = u[0]; P[1] = u[1]; P[2] = u[2]; P[3] = u[3];
    #pragma unroll
    for (int q = 4; q < 8; ++q) P[q] = u[q] + u[q-4];
}

__device__ __forceinline__ void loadrow8(const float* p, float v[8]) {
    float4 a = *reinterpret_cast<const float4*>(p);
    float4 b = *reinterpret_cast<const float4*>(p + 4);
    v[0]=a.x; v[1]=a.y; v[2]=a.z; v[3]=a.w;
    v[4]=b.x; v[5]=b.y; v[6]=b.z; v[7]=b.w;
}
__device__ __forceinline__ void storerow8(float* __restrict__ p, const float v[8]) {
    *reinterpret_cast<float4*>(p)     = make_float4(v[0],v[1],v[2],v[3]);
    *reinterpret_cast<float4*>(p + 4) = make_float4(v[4],v[5],v[6],v[7]);
}

// ---------------- hand-held vmem ops (invisible to SIInsertWaitcnts) ----------------
__device__ __forceinline__ void aload2(f32x4 &d0, f32x4 &d1, const float* p) {
    asm volatile("global_load_dwordx4 %0, %2, off\n\t"
                 "global_load_dwordx4 %1, %2, off offset:16"
                 : "=&v"(d0), "=&v"(d1) : "v"(p) : "memory");
}
__device__ __forceinline__ void astore2(f32x4 d0, f32x4 d1, float* p) {
    asm volatile("global_store_dwordx4 %2, %0, off\n\t"
                 "global_store_dwordx4 %2, %1, off offset:16"
                 :: "v"(d0), "v"(d1), "v"(p) : "memory");
}
template<int N> __device__ __forceinline__ void waitcnt_vm() {
    asm volatile("s_waitcnt vmcnt(%0)" :: "i"(N) : "memory");
}

struct Buf { f32x4 e0, e1, w0, w1; };   // one (Ee,W) row fragment: 16 VGPRs

// ---------------- energy: tiled outer-product GEMM ----------------
__global__ __launch_bounds__(256) void energy_kernel(
        const float* __restrict__ text, const float* __restrict__ mel,
        const float* __restrict__ noise, const float* __restrict__ ratio,
        float* __restrict__ e) {
    __shared__ float melS[64][65];
    __shared__ float texS[8][65];
    int b  = blockIdx.x;
    int i0 = blockIdx.y * 8;
    int j0 = blockIdx.z * 64;
    int t = threadIdx.x;
    int jj = t & 63, ig = t >> 6;
    float acc0 = 0.f, acc1 = 0.f;
    for (int cc = 0; cc < CC; cc += 64) {
        #pragma unroll
        for (int k = 0; k < 4; ++k) {
            int idx = t + k * 256;
            int row = idx >> 4, seg = idx & 15;
            float4 v = *reinterpret_cast<const float4*>(
                mel + (size_t)(b * JJ + j0 + row) * CC + cc + seg * 4);
            melS[row][seg*4+0] = v.x; melS[row][seg*4+1] = v.y;
            melS[row][seg*4+2] = v.z; melS[row][seg*4+3] = v.w;
        }
        if (t < 128) {
            int row = t >> 4, seg = t & 15;
            float4 v = *reinterpret_cast<const float4*>(
                text + (size_t)(b * II + i0 + row) * CC + cc + seg * 4);
            texS[row][seg*4+0] = v.x; texS[row][seg*4+1] = v.y;
            texS[row][seg*4+2] = v.z; texS[row][seg*4+3] = v.w;
        }
        __syncthreads();
        #pragma unroll 8
        for (int c = 0; c < 64; ++c) {
            float m = melS[jj][c];
            acc0 = fmaf(m, texS[ig*2+0][c], acc0);
            acc1 = fmaf(m, texS[ig*2+1][c], acc1);
        }
        __syncthreads();
    }
    float temp = 0.1f + 0.9f * ratio[0];
    float rtmp = 1.0f / temp;
    int r0 = (b * II + i0 + ig*2 + 0) * JJ + j0 + jj;
    int r1 = (b * II + i0 + ig*2 + 1) * JJ + j0 + jj;
    e[r0] = (acc0 * (1.0f/256.0f) + noise[r0]) * rtmp;
    e[r1] = (acc1 * (1.0f/256.0f) + noise[r1]) * rtmp;
}

// ---------------- per row: Ee = exp(e - rowmax); Wa = 1/suffix_sum; Wb = 1/prefix_sum ----------------
__global__ __launch_bounds__(64) void dscan_kernel(
        const float* __restrict__ e, float* __restrict__ Ee,
        float* __restrict__ Wa, float* __restrict__ Wb) {
    int row = blockIdx.x;
    int lane = threadIdx.x;
    float v[8];
    loadrow8(e + row * JJ + lane * 8, v);
    float m = v[0];
    #pragma unroll
    for (int q = 1; q < 8; ++q) m = fmaxf(m, v[q]);
    #pragma unroll
    for (int d = 1; d < 64; d <<= 1) m = fmaxf(m, __shfl_xor(m, d, 64));
    float x[8];
    #pragma unroll
    for (int q = 0; q < 8; ++q) x[q] = __expf(v[q] - m);
    storerow8(Ee + row * JJ + lane * 8, x);
    float run = 0.f, P[8];
    #pragma unroll
    for (int q = 0; q < 8; ++q) { run += x[q]; P[q] = run; }
    float sc = wscan_incl(run);
    float cp = lane_shr1(sc);
    float run2 = 0.f, S[8];
    #pragma unroll
    for (int q = 7; q >= 0; --q) { run2 += x[q]; S[q] = run2; }
    float sd = run2;
    #pragma unroll
    for (int d = 1; d < 64; d <<= 1) { float o = __shfl_down(sd, d, 64); sd += (lane + d < 64) ? o : 0.0f; }
    float cs = __shfl_down(sd, 1, 64); if (lane == 63) cs = 0.f;
    float wa[8], wb[8];
    #pragma unroll
    for (int q = 0; q < 8; ++q) {
        wa[q] = 1.0f / (S[q] + cs);
        wb[q] = 1.0f / (P[q] + cp);
    }
    storerow8(Wa + row * JJ + lane * 8, wa);
    storerow8(Wb + row * JJ + lane * 8, wb);
}

// ======================= scan_ab: all-asm vmem, ring depth 8 =======================
// R7 measured step ~= ack/3 (790cy): the vmcnt wait transitively requires the
// STORE-ACK of our own row stores issued 3 steps earlier (~2400cy ack to the
// HBM-backed workspace). Fix: ring depth 8 / distance 7 for BOTH the Buf ring
// and the P-register ring, so the wait needs stores 7 steps old:
// step >= ack/7 ~= 350cy ~= the compute floor.
// Per step vmem (all inline asm): [2 stores][4 loads][wait vmcnt(VM)].
// Ledger (6 ops/step, prologue 28): warm-up 30/32/34/36/38/40/42, steady 42,
// tail 38/34/30/26/22/18/14. ca/cb go to LDS (lgkm domain, not counted).

template<bool NORM, int VM, bool PF>
__device__ __forceinline__ void astep(
    int i, int lane, int off,
    const float (&pin)[8], float (&pout)[8], float& c,
    Buf& C, Buf& L,
    const float* __restrict__ EeB, const float* __restrict__ WaB,
    float* __restrict__ paB, float* ldsC)
{
    {
        f32x4 s0 = {pin[0], pin[1], pin[2], pin[3]};
        f32x4 s1 = {pin[4], pin[5], pin[6], pin[7]};
        astore2(s0, s1, paB + (size_t)(i - 1) * JJ + off);   // pin holds row i-1
    }
    if (lane == 0) ldsC[i - 1] = c;
    if (PF) {
        aload2(L.e0, L.e1, EeB + (size_t)(i + 7) * JJ + off);
        aload2(L.w0, L.w1, WaB + (size_t)(i + 7) * JJ + off);
    }
    waitcnt_vm<VM>();
    __builtin_amdgcn_sched_barrier(0);   // rule #18: keep consumers behind the wait
    float CE[8] = {C.e0[0],C.e0[1],C.e0[2],C.e0[3],C.e1[0],C.e1[1],C.e1[2],C.e1[3]};
    float CW[8] = {C.w0[0],C.w0[1],C.w0[2],C.w0[3],C.w1[0],C.w1[1],C.w1[2],C.w1[3]};

    float pup = lane_shr1(pin[7]);
    float y[8];
    y[0] = pup * CW[0];
    #pragma unroll
    for (int q = 1; q < 8; ++q) y[q] = pin[q-1] * CW[q];
    float zz[8];
    #pragma unroll
    for (int q = 0; q < 7; ++q) zz[q] = pin[q];
    zz[7] = (lane == 63) ? 0.0f : pin[7];
    float Y[8], Z[8];
    tree_prefix8(y, Y);
    tree_prefix8(zz, Z);
    float sy = wscan_incl(Y[7]);
    float sz = wscan_incl(Z[7]);
    float oy = lane_shr1(sy);
    float oz = lane_shr1(sz);
    float T  = bcast63(sz);
    #pragma unroll
    for (int q = 0; q < 8; ++q) {
        float S1 = oy + Y[q];                              // incl prefix of y
        float S2 = fmaxf(T - (oz + Z[q]) + zz[q], 0.0f);   // incl suffix of z
        pout[q] = fmaf(CE[q], S1, K10 * S2);
    }
    if (NORM) {
        float Tc = fmaxf(T, 1e-30f);
        float rT = __builtin_amdgcn_rcpf(Tc);
        c += __logf(Tc);
        #pragma unroll
        for (int q = 0; q < 8; ++q) pout[q] *= rT;
    }
}

template<bool NORM, int VM, bool PF>
__device__ __forceinline__ void bstep(
    int i, int lane, int off,
    const float (&pin)[8], float (&pout)[8], float& c,
    Buf& C, Buf& L,
    const float* __restrict__ EeB, const float* __restrict__ WbB,
    float* __restrict__ pbB, float* ldsC)
{
    {
        f32x4 s0 = {pin[0], pin[1], pin[2], pin[3]};
        f32x4 s1 = {pin[4], pin[5], pin[6], pin[7]};
        astore2(s0, s1, pbB + (size_t)(i + 1) * JJ + off);   // pin holds row i+1
    }
    if (lane == 0) ldsC[i + 1] = c;
    if (PF) {
        aload2(L.e0, L.e1, EeB + (size_t)(i - 7) * JJ + 504 - 8 * lane);
        aload2(L.w0, L.w1, WbB + (size_t)(i - 7) * JJ + 504 - 8 * lane);
    }
    waitcnt_vm<VM>();
    __builtin_amdgcn_sched_barrier(0);
    // reversed: CE[q] = rowdata[7-q]  (rowdata[k] = row[504-8*lane+k])
    float CE[8] = {C.e1[3],C.e1[2],C.e1[1],C.e1[0],C.e0[3],C.e0[2],C.e0[1],C.e0[0]};
    float CW[8] = {C.w1[3],C.w1[2],C.w1[1],C.w1[0],C.w0[3],C.w0[2],C.w0[1],C.w0[0]};

    float pup = lane_shr1(pin[7]);
    float pn[8];
    pn[0] = pup;
    #pragma unroll
    for (int q = 1; q < 8; ++q) pn[q] = pin[q-1];
    float w[8];
    #pragma unroll
    for (int q = 0; q < 8; ++q) w[q] = pn[q] * CW[q];
    float W[8], N[8];
    tree_prefix8(w, W);
    tree_prefix8(pn, N);
    float sw = wscan_incl(W[7]);
    float sn = wscan_incl(N[7]);
    float ow = lane_shr1(sw);
    float on = lane_shr1(sn);
    float T  = bcast63(sn);
    #pragma unroll
    for (int q = 0; q < 8; ++q) {
        float QA = ow + W[q];                    // incl prefix of w
        float QB = fmaxf(T - (on + N[q]), 0.0f); // excl suffix of pn
        pout[q] = fmaf(CE[q], QA, K10 * QB);
    }
    if (NORM) {
        float Tc = fmaxf(T, 1e-30f);
        float rT = __builtin_amdgcn_rcpf(Tc);
        c += __logf(Tc);
        #pragma unroll
        for (int q = 0; q < 8; ++q) pout[q] *= rT;
    }
}

__global__ __launch_bounds__(64, 1) void scan_ab_kernel(
        const float* __restrict__ Ee, const float* __restrict__ Wa,
        const float* __restrict__ Wb,
        float* __restrict__ pa, float* __restrict__ pb,
        float* __restrict__ ca, float* __restrict__ cb) {
    __shared__ float ldsC[II];
    int b = blockIdx.x >> 1, dir = blockIdx.x & 1;
    int lane = threadIdx.x, off = lane * 8;
    size_t base = (size_t)b * II * JJ;
    float P0[8],P1[8],P2[8],P3[8],P4[8],P5[8],P6[8],P7[8], c = 0.0f;
    Buf B0,B1,B2,B3,B4,B5,B6,B7;

    if (dir == 0) {
        const float* EeB = Ee + base; const float* WaB = Wa + base;
        float* paB = pa + base; float* caB = ca + b * II;
        // row 0 via compiler loads (their auto-wait lands before our asm stream)
        float e0r[8];
        loadrow8(EeB + off, e0r);
        float wa00 = WaB[0];
        #pragma unroll
        for (int q = 0; q < 8; ++q) P0[q] = e0r[q] * wa00;   // row 0
        __builtin_amdgcn_sched_barrier(0);
        // asm prefetch rows 1..7 -> B1..B7 (28 ops)
        aload2(B1.e0, B1.e1, EeB + (size_t)1*JJ + off); aload2(B1.w0, B1.w1, WaB + (size_t)1*JJ + off);
        aload2(B2.e0, B2.e1, EeB + (size_t)2*JJ + off); aload2(B2.w0, B2.w1, WaB + (size_t)2*JJ + off);
        aload2(B3.e0, B3.e1, EeB + (size_t)3*JJ + off); aload2(B3.w0, B3.w1, WaB + (size_t)3*JJ + off);
        aload2(B4.e0, B4.e1, EeB + (size_t)4*JJ + off); aload2(B4.w0, B4.w1, WaB + (size_t)4*JJ + off);
        aload2(B5.e0, B5.e1, EeB + (size_t)5*JJ + off); aload2(B5.w0, B5.w1, WaB + (size_t)5*JJ + off);
        aload2(B6.e0, B6.e1, EeB + (size_t)6*JJ + off); aload2(B6.w0, B6.w1, WaB + (size_t)6*JJ + off);
        aload2(B7.e0, B7.e1, EeB + (size_t)7*JJ + off); aload2(B7.w0, B7.w1, WaB + (size_t)7*JJ + off);
        // warm-up steps 1..7
        astep<true ,30,true>(1, lane, off, P0, P1, c, B1, B0, EeB, WaB, paB, ldsC);
        astep<false,32,true>(2, lane, off, P1, P2, c, B2, B1, EeB, WaB, paB, ldsC);
        astep<false,34,true>(3, lane, off, P2, P3, c, B3, B2, EeB, WaB, paB, ldsC);
        astep<false,36,true>(4, lane, off, P3, P4, c, B4, B3, EeB, WaB, paB, ldsC);
        astep<true ,38,true>(5, lane, off, P4, P5, c, B5, B4, EeB, WaB, paB, ldsC);
        astep<false,40,true>(6, lane, off, P5, P6, c, B6, B5, EeB, WaB, paB, ldsC);
        astep<false,42,true>(7, lane, off, P6, P7, c, B7, B6, EeB, WaB, paB, ldsC);
        #pragma unroll 1
        for (int d = 0; d < 14; ++d) {        // steps 8..119
            int ib = 8 + 8 * d;
            astep<false,42,true>(ib+0, lane, off, P7, P0, c, B0, B7, EeB, WaB, paB, ldsC);
            astep<true ,42,true>(ib+1, lane, off, P0, P1, c, B1, B0, EeB, WaB, paB, ldsC);
            astep<false,42,true>(ib+2, lane, off, P1, P2, c, B2, B1, EeB, WaB, paB, ldsC);
            astep<false,42,true>(ib+3, lane, off, P2, P3, c, B3, B2, EeB, WaB, paB, ldsC);
            astep<false,42,true>(ib+4, lane, off, P3, P4, c, B4, B3, EeB, WaB, paB, ldsC);
            astep<true ,42,true>(ib+5, lane, off, P4, P5, c, B5, B4, EeB, WaB, paB, ldsC);
            astep<false,42,true>(ib+6, lane, off, P5, P6, c, B6, B5, EeB, WaB, paB, ldsC);
            astep<false,42,true>(ib+7, lane, off, P6, P7, c, B7, B6, EeB, WaB, paB, ldsC);
        }
        astep<false,42,true >(120, lane, off, P7, P0, c, B0, B7, EeB, WaB, paB, ldsC);
        // tail 121..127 (no PF)
        astep<true ,38,false>(121, lane, off, P0, P1, c, B1, B0, EeB, WaB, paB, ldsC);
        astep<false,34,false>(122, lane, off, P1, P2, c, B2, B1, EeB, WaB, paB, ldsC);
        astep<false,30,false>(123, lane, off, P2, P3, c, B3, B2, EeB, WaB, paB, ldsC);
        astep<false,26,false>(124, lane, off, P3, P4, c, B4, B3, EeB, WaB, paB, ldsC);
        astep<true ,22,false>(125, lane, off, P4, P5, c, B5, B4, EeB, WaB, paB, ldsC);
        astep<false,18,false>(126, lane, off, P5, P6, c, B6, B5, EeB, WaB, paB, ldsC);
        astep<false,14,false>(127, lane, off, P6, P7, c, B7, B6, EeB, WaB, paB, ldsC);
        storerow8(paB + (size_t)127 * JJ + off, P7);
        if (lane == 0) ldsC[127] = c;
        waitcnt_vm<0>();                       // drain our asm stores before endpgm
        caB[lane]      = ldsC[lane];
        caB[lane + 64] = ldsC[lane + 64];
    } else {
        const float* EeB = Ee + base; const float* WbB = Wb + base;
        float* pbB = pb + base; float* cbB = cb + b * II;
        #pragma unroll
        for (int q = 0; q < 8; ++q) P7[q] = 0.0f;
        P7[0] = (lane == 0) ? 1.0f : 0.0f;   // row 127 (j'=0 <-> orig j=J-1)
        // asm prefetch rows 126..120 -> B6..B0 (reversed addressing, row r -> B[r&7])
        aload2(B6.e0, B6.e1, EeB + (size_t)126*JJ + 504 - 8*lane); aload2(B6.w0, B6.w1, WbB + (size_t)126*JJ + 504 - 8*lane);
        aload2(B5.e0, B5.e1, EeB + (size_t)125*JJ + 504 - 8*lane); aload2(B5.w0, B5.w1, WbB + (size_t)125*JJ + 504 - 8*lane);
        aload2(B4.e0, B4.e1, EeB + (size_t)124*JJ + 504 - 8*lane); aload2(B4.w0, B4.w1, WbB + (size_t)124*JJ + 504 - 8*lane);
        aload2(B3.e0, B3.e1, EeB + (size_t)123*JJ + 504 - 8*lane); aload2(B3.w0, B3.w1, WbB + (size_t)123*JJ + 504 - 8*lane);
        aload2(B2.e0, B2.e1, EeB + (size_t)122*JJ + 504 - 8*lane); aload2(B2.w0, B2.w1, WbB + (size_t)122*JJ + 504 - 8*lane);
        aload2(B1.e0, B1.e1, EeB + (size_t)121*JJ + 504 - 8*lane); aload2(B1.w0, B1.w1, WbB + (size_t)121*JJ + 504 - 8*lane);
        aload2(B0.e0, B0.e1, EeB + (size_t)120*JJ + 504 - 8*lane); aload2(B0.w0, B0.w1, WbB + (size_t)120*JJ + 504 - 8*lane);
        // warm-up steps 126..120
        bstep<true ,30,true>(126, lane, off, P7, P6, c, B6, B7, EeB, WbB, pbB, ldsC);
        bstep<false,32,true>(125, lane, off, P6, P5, c, B5, B6, EeB, WbB, pbB, ldsC);
        bstep<false,34,true>(124, lane, off, P5, P4, c, B4, B5, EeB, WbB, pbB, ldsC);
        bstep<false,36,true>(123, lane, off, P4, P3, c, B3, B4, EeB, WbB, pbB, ldsC);
        bstep<true ,38,true>(122, lane, off, P3, P2, c, B2, B3, EeB, WbB, pbB, ldsC);
        bstep<false,40,true>(121, lane, off, P2, P1, c, B1, B2, EeB, WbB, pbB, ldsC);
        bstep<false,42,true>(120, lane, off, P1, P0, c, B0, B1, EeB, WbB, pbB, ldsC);
        #pragma unroll 1
        for (int d = 0; d < 14; ++d) {        // steps 119..8
            int ib = 119 - 8 * d;
            bstep<false,42,true>(ib-0, lane, off, P0, P7, c, B7, B0, EeB, WbB, pbB, ldsC);
            bstep<true ,42,true>(ib-1, lane, off, P7, P6, c, B6, B7, EeB, WbB, pbB, ldsC);
            bstep<false,42,true>(ib-2, lane, off, P6, P5, c, B5, B6, EeB, WbB, pbB, ldsC);
            bstep<false,42,true>(ib-3, lane, off, P5, P4, c, B4, B5, EeB, WbB, pbB, ldsC);
            bstep<false,42,true>(ib-4, lane, off, P4, P3, c, B3, B4, EeB, WbB, pbB, ldsC);
            bstep<true ,42,true>(ib-5, lane, off, P3, P2, c, B2, B3, EeB, WbB, pbB, ldsC);
            bstep<false,42,true>(ib-6, lane, off, P2, P1, c, B1, B2, EeB, WbB, pbB, ldsC);
            bstep<false,42,true>(ib-7, lane, off, P1, P0, c, B0, B1, EeB, WbB, pbB, ldsC);
        }
        bstep<false,42,true >(7, lane, off, P0, P7, c, B7, B0, EeB, WbB, pbB, ldsC);
        // tail 6..0 (no PF)
        bstep<true ,38,false>(6, lane, off, P7, P6, c, B6, B7, EeB, WbB, pbB, ldsC);
        bstep<false,34,false>(5, lane, off, P6, P5, c, B5, B6, EeB, WbB, pbB, ldsC);
        bstep<false,30,false>(4, lane, off, P5, P4, c, B4, B5, EeB, WbB, pbB, ldsC);
        bstep<false,26,false>(3, lane, off, P4, P3, c, B3, B4, EeB, WbB, pbB, ldsC);
        bstep<true ,22,false>(2, lane, off, P3, P2, c, B2, B3, EeB, WbB, pbB, ldsC);
        bstep<false,18,false>(1, lane, off, P2, P1, c, B1, B2, EeB, WbB, pbB, ldsC);
        bstep<false,14,false>(0, lane, off, P1, P0, c, B0, B1, EeB, WbB, pbB, ldsC);
        storerow8(pbB + off, P0);           // row 0
        if (lane == 0) ldsC[0] = c;
        waitcnt_vm<0>();                    // drain our asm stores before endpgm
        cbB[lane]      = ldsC[lane];
        cbB[lane + 64] = ldsC[lane + 64];
    }
}

// ---------------- fused gamma + expand ----------------
__global__ __launch_bounds__(256) void gamma_expand_kernel(
        const float* __restrict__ pa, const float* __restrict__ pb,
        const float* __restrict__ ca, const float* __restrict__ cb,
        const float* __restrict__ text, const float* __restrict__ mmask,
        float* __restrict__ gamma_out, float* __restrict__ expanded) {
    __shared__ float wt[II][9];      // stride 9: phase-A writes ~2-way conflicts (free)
    __shared__ float Ei[II];
    __shared__ float red[8][33];     // partial column sums [q][ic]
    int b   = blockIdx.x >> 6;       // 64 tiles per batch
    int jj0 = (blockIdx.x & 63) * 8;
    int t = threadIdx.x;
    int q = t & 7, ic = t >> 3;      // ic 0..31 handles i = 4*ic..4*ic+3

    if (t < II) Ei[t] = ca[b*II + t] + cb[b*II + t];
    __syncthreads();
    float maxc = Ei[0];
    #pragma unroll 16
    for (int i = 1; i < II; ++i) maxc = fmaxf(maxc, Ei[i]);
    __syncthreads();
    if (t < II) Ei[t] = __expf(Ei[t] - maxc);
    __syncthreads();

    size_t idx0  = (size_t)b * II * JJ + jj0 + q;
    size_t idx0r = (size_t)b * II * JJ + (JJ - 1 - jj0 - q);   // pb stored j-reversed
    float d = 0.f;
    #pragma unroll
    for (int k = 0; k < 4; ++k) {
        int i = ic * 4 + k;
        float P = pa[idx0 + (size_t)i * JJ] * pb[idx0r + (size_t)i * JJ] * Ei[i];
        wt[i][q] = P;
        d += P;
    }
    red[q][ic] = d;
    __syncthreads();
    if (t < 8) {
        float s = 0.f;
        #pragma unroll
        for (int k = 0; k < 32; ++k) s += red[t][k];
        red[t][32] = 1.0f / fmaxf(s, 1e-37f);
    }
    __syncthreads();
    float rD = red[q][32];
    #pragma unroll
    for (int k = 0; k < 4; ++k) {
        int i = ic * 4 + k;
        float P = wt[i][q] * rD;
        wt[i][q] = P;
        gamma_out[idx0 + (size_t)i * JJ] = fmaxf(__logf(P), -1e30f);  // log(0)=-inf -> -1e30
    }
    __syncthreads();

    // phase B: expanded[b, jj0+qq, c=t] = mmask * sum_i wt[i][qq] * text[b,i,t]
    float acc[8] = {0,0,0,0,0,0,0,0};
    const float* txb = text + (size_t)b * II * CC + t;
    #pragma unroll 4
    for (int i = 0; i < II; ++i) {
        float tv = txb[(size_t)i * CC];
        #pragma unroll
        for (int qq = 0; qq < 8; ++qq) acc[qq] = fmaf(wt[i][qq], tv, acc[qq]);
    }
    #pragma unroll
    for (int qq = 0; qq < 8; ++qq) {
        expanded[(size_t)(b * JJ + jj0 + qq) * CC + t] =
            acc[qq] * mmask[b * JJ + jj0 + qq];
    }
}

extern "C" void kernel_launch(void* const* d_in, const int* in_sizes, int n_in,
                              void* d_out, int out_size, void* d_ws, size_t ws_size,
                              hipStream_t stream) {
    const float* text  = (const float*)d_in[0];
    const float* mel   = (const float*)d_in[1];
    const float* mmask = (const float*)d_in[3];
    const float* noise = (const float*)d_in[4];
    const float* ratio = (const float*)d_in[5];
    float* gamma_out = (float*)d_out;            // B*I*J floats
    float* expanded  = (float*)d_out + NEL;      // B*J*C floats

    float* ws = (float*)d_ws;
    float* Ee = ws;                  // NEL
    float* Wa = ws +   NEL;          // NEL
    float* Wb = ws + 2*NEL;          // NEL
    float* pa = ws + 3*NEL;          // NEL (aliased: e lives here pre-scan)
    float* pb = ws + 4*NEL;          // NEL (j-reversed layout)
    float* ca = ws + 5*NEL;          // BB*II
    float* cb = ws + 5*NEL + BB*II;  // BB*II
    float* e  = pa;                  // e dead once scan_ab starts writing pa

    hipLaunchKernelGGL(energy_kernel, dim3(BB, II/8, JJ/64), dim3(256), 0, stream,
                       text, mel, noise, ratio, e);
    hipLaunchKernelGGL(dscan_kernel, dim3(BB*II), dim3(64), 0, stream, e, Ee, Wa, Wb);
    hipLaunchKernelGGL(scan_ab_kernel, dim3(BB*2), dim3(64), 0, stream,
                       Ee, Wa, Wb, pa, pb, ca, cb);
    hipLaunchKernelGGL(gamma_expand_kernel, dim3(BB*64), dim3(256), 0, stream,
                       pa, pb, ca, cb, text, mmask, gamma_out, expanded);
}

// Round 9
// 130.110 us; speedup vs baseline: 1.0025x; 1.0025x over previous
//
#include <hip/hip_runtime.h>
#include <math.h>

#define BB 2
#define II 128
#define JJ 512
#define CC 256
#define NEL (BB*II*JJ)   // 131072
#define NINF (-INFINITY)
#define K10 4.5399929762484854e-5f   // exp(-10)

typedef float f32x4 __attribute__((ext_vector_type(4)));   // asm-operand-safe vec4

// ---------------- DPP wave64 primitives ----------------
template<int CTRL, int RM = 0xf, int BM = 0xf, bool BC = true>
__device__ __forceinline__ float dppf(float x) {
    return __int_as_float(__builtin_amdgcn_update_dpp(
        0, __float_as_int(x), CTRL, RM, BM, BC));
}
__device__ __forceinline__ float wscan_incl(float x) {
    x += dppf<0x111>(x);              // row_shr:1
    x += dppf<0x112>(x);              // row_shr:2
    x += dppf<0x114>(x);              // row_shr:4
    x += dppf<0x118>(x);              // row_shr:8
    x += dppf<0x142, 0xa>(x);         // row_bcast:15 -> rows 1,3
    x += dppf<0x143, 0xc>(x);         // row_bcast:31 -> rows 2,3
    return x;
}
__device__ __forceinline__ float lane_shr1(float x) { return dppf<0x138>(x); }
__device__ __forceinline__ float bcast63(float x) {
    return __int_as_float(__builtin_amdgcn_readlane(__float_as_int(x), 63));
}

// in-lane inclusive prefix sum, tree form (depth 3)
__device__ __forceinline__ void tree_prefix8(const float x[8], float P[8]) {
    float t[8];
    t[0] = x[0];
    #pragma unroll
    for (int q = 1; q < 8; ++q) t[q] = x[q] + x[q-1];
    float u[8];
    u[0] = t[0]; u[1] = t[1];
    #pragma unroll
    for (int q = 2; q < 8; ++q) u[q] = t[q] + t[q-2];
    P[0] = u[0]; P[1] = u[1]; P[2] = u[2]; P[3] = u[3];
    #pragma unroll
    for (int q = 4; q < 8; ++q) P[q] = u[q] + u[q-4];
}

__device__ __forceinline__ void loadrow8(const float* p, float v[8]) {
    float4 a = *reinterpret_cast<const float4*>(p);
    float4 b = *reinterpret_cast<const float4*>(p + 4);
    v[0]=a.x; v[1]=a.y; v[2]=a.z; v[3]=a.w;
    v[4]=b.x; v[5]=b.y; v[6]=b.z; v[7]=b.w;
}
__device__ __forceinline__ void storerow8(float* __restrict__ p, const float v[8]) {
    *reinterpret_cast<float4*>(p)     = make_float4(v[0],v[1],v[2],v[3]);
    *reinterpret_cast<float4*>(p + 4) = make_float4(v[4],v[5],v[6],v[7]);
}

// ---------------- hand-held vmem ops (invisible to SIInsertWaitcnts) ----------------
__device__ __forceinline__ void aload2(f32x4 &d0, f32x4 &d1, const float* p) {
    asm volatile("global_load_dwordx4 %0, %2, off\n\t"
                 "global_load_dwordx4 %1, %2, off offset:16"
                 : "=&v"(d0), "=&v"(d1) : "v"(p) : "memory");
}
__device__ __forceinline__ void astore2(f32x4 d0, f32x4 d1, float* p) {
    asm volatile("global_store_dwordx4 %2, %0, off\n\t"
                 "global_store_dwordx4 %2, %1, off offset:16"
                 :: "v"(d0), "v"(d1), "v"(p) : "memory");
}
template<int N> __device__ __forceinline__ void waitcnt_vm() {
    asm volatile("s_waitcnt vmcnt(%0)" :: "i"(N) : "memory");
}

struct Buf { f32x4 e0, e1, w0, w1; };   // one (Ee,W) row fragment: 16 VGPRs

// ---------------- energy: tiled outer-product GEMM ----------------
__global__ __launch_bounds__(256) void energy_kernel(
        const float* __restrict__ text, const float* __restrict__ mel,
        const float* __restrict__ noise, const float* __restrict__ ratio,
        float* __restrict__ e) {
    __shared__ float melS[64][65];
    __shared__ float texS[8][65];
    int b  = blockIdx.x;
    int i0 = blockIdx.y * 8;
    int j0 = blockIdx.z * 64;
    int t = threadIdx.x;
    int jj = t & 63, ig = t >> 6;
    float acc0 = 0.f, acc1 = 0.f;
    for (int cc = 0; cc < CC; cc += 64) {
        #pragma unroll
        for (int k = 0; k < 4; ++k) {
            int idx = t + k * 256;
            int row = idx >> 4, seg = idx & 15;
            float4 v = *reinterpret_cast<const float4*>(
                mel + (size_t)(b * JJ + j0 + row) * CC + cc + seg * 4);
            melS[row][seg*4+0] = v.x; melS[row][seg*4+1] = v.y;
            melS[row][seg*4+2] = v.z; melS[row][seg*4+3] = v.w;
        }
        if (t < 128) {
            int row = t >> 4, seg = t & 15;
            float4 v = *reinterpret_cast<const float4*>(
                text + (size_t)(b * II + i0 + row) * CC + cc + seg * 4);
            texS[row][seg*4+0] = v.x; texS[row][seg*4+1] = v.y;
            texS[row][seg*4+2] = v.z; texS[row][seg*4+3] = v.w;
        }
        __syncthreads();
        #pragma unroll 8
        for (int c = 0; c < 64; ++c) {
            float m = melS[jj][c];
            acc0 = fmaf(m, texS[ig*2+0][c], acc0);
            acc1 = fmaf(m, texS[ig*2+1][c], acc1);
        }
        __syncthreads();
    }
    float temp = 0.1f + 0.9f * ratio[0];
    float rtmp = 1.0f / temp;
    int r0 = (b * II + i0 + ig*2 + 0) * JJ + j0 + jj;
    int r1 = (b * II + i0 + ig*2 + 1) * JJ + j0 + jj;
    e[r0] = (acc0 * (1.0f/256.0f) + noise[r0]) * rtmp;
    e[r1] = (acc1 * (1.0f/256.0f) + noise[r1]) * rtmp;
}

// ---------------- per row: Ee = exp(e - rowmax); Wa = 1/suffix_sum; Wb = 1/prefix_sum ----------------
__global__ __launch_bounds__(64) void dscan_kernel(
        const float* __restrict__ e, float* __restrict__ Ee,
        float* __restrict__ Wa, float* __restrict__ Wb) {
    int row = blockIdx.x;
    int lane = threadIdx.x;
    float v[8];
    loadrow8(e + row * JJ + lane * 8, v);
    float m = v[0];
    #pragma unroll
    for (int q = 1; q < 8; ++q) m = fmaxf(m, v[q]);
    #pragma unroll
    for (int d = 1; d < 64; d <<= 1) m = fmaxf(m, __shfl_xor(m, d, 64));
    float x[8];
    #pragma unroll
    for (int q = 0; q < 8; ++q) x[q] = __expf(v[q] - m);
    storerow8(Ee + row * JJ + lane * 8, x);
    float run = 0.f, P[8];
    #pragma unroll
    for (int q = 0; q < 8; ++q) { run += x[q]; P[q] = run; }
    float sc = wscan_incl(run);
    float cp = lane_shr1(sc);
    float run2 = 0.f, S[8];
    #pragma unroll
    for (int q = 7; q >= 0; --q) { run2 += x[q]; S[q] = run2; }
    float sd = run2;
    #pragma unroll
    for (int d = 1; d < 64; d <<= 1) { float o = __shfl_down(sd, d, 64); sd += (lane + d < 64) ? o : 0.0f; }
    float cs = __shfl_down(sd, 1, 64); if (lane == 63) cs = 0.f;
    float wa[8], wb[8];
    #pragma unroll
    for (int q = 0; q < 8; ++q) {
        wa[q] = 1.0f / (S[q] + cs);
        wb[q] = 1.0f / (P[q] + cp);
    }
    storerow8(Wa + row * JJ + lane * 8, wa);
    storerow8(Wb + row * JJ + lane * 8, wb);
}

// ======================= scan_ab: all-asm vmem, distance 5, peak in-flight 32 =======================
// Empirical law (R7/R8/R4): step >= store-ack/d (ack ~2400cy, in-order vmcnt
// retirement forces our own stores), AND a collapse to ~1300cy/step when peak
// outstanding vmem > ~32 (R8/R4 at 48, independent of reg pressure).
// Distance 5 puts store age at 5*step (>= ack at step ~480) with peak = 32.
// In-place Buf ring of 5: consume slot i%5, then reload row i+5 into the SAME
// slot (distance == ring size, no extra regs). P ring 10 (unroll 10): store-
// source regs overwritten 9 steps after their store, covered by the wait.
// Per step: [2 stores][wait VM][consume][4 loads][compute]. Ledger: VM = #ops
// younger than row i's loads = warm 18/20/22/24/26, steady 26, tail 26/22/18/14/10.
// NORM cadence 5 (divides unroll 10; was 4).

template<bool NORM, int VM, bool PF>
__device__ __forceinline__ void astep(
    int i, int lane, int off,
    const float (&pin)[8], float (&pout)[8], float& c,
    Buf& B,
    const float* __restrict__ EeB, const float* __restrict__ WaB,
    float* __restrict__ paB, float* ldsC)
{
    {
        f32x4 s0 = {pin[0], pin[1], pin[2], pin[3]};
        f32x4 s1 = {pin[4], pin[5], pin[6], pin[7]};
        astore2(s0, s1, paB + (size_t)(i - 1) * JJ + off);   // pin holds row i-1
    }
    if (lane == 0) ldsC[i - 1] = c;
    waitcnt_vm<VM>();
    __builtin_amdgcn_sched_barrier(0);   // rule #18: keep Buf consumers behind the wait
    float CE[8] = {B.e0[0],B.e0[1],B.e0[2],B.e0[3],B.e1[0],B.e1[1],B.e1[2],B.e1[3]};
    float CW[8] = {B.w0[0],B.w0[1],B.w0[2],B.w0[3],B.w1[0],B.w1[1],B.w1[2],B.w1[3]};
    if (PF) {   // reload same slot with row i+5 (in-place: distance == ring size)
        aload2(B.e0, B.e1, EeB + (size_t)(i + 5) * JJ + off);
        aload2(B.w0, B.w1, WaB + (size_t)(i + 5) * JJ + off);
    }

    float pup = lane_shr1(pin[7]);
    float y[8];
    y[0] = pup * CW[0];
    #pragma unroll
    for (int q = 1; q < 8; ++q) y[q] = pin[q-1] * CW[q];
    float zz[8];
    #pragma unroll
    for (int q = 0; q < 7; ++q) zz[q] = pin[q];
    zz[7] = (lane == 63) ? 0.0f : pin[7];
    float Y[8], Z[8];
    tree_prefix8(y, Y);
    tree_prefix8(zz, Z);
    float sy = wscan_incl(Y[7]);
    float sz = wscan_incl(Z[7]);
    float oy = lane_shr1(sy);
    float oz = lane_shr1(sz);
    float T  = bcast63(sz);
    #pragma unroll
    for (int q = 0; q < 8; ++q) {
        float S1 = oy + Y[q];                              // incl prefix of y
        float S2 = fmaxf(T - (oz + Z[q]) + zz[q], 0.0f);   // incl suffix of z
        pout[q] = fmaf(CE[q], S1, K10 * S2);
    }
    if (NORM) {
        float Tc = fmaxf(T, 1e-30f);
        float rT = __builtin_amdgcn_rcpf(Tc);
        c += __logf(Tc);
        #pragma unroll
        for (int q = 0; q < 8; ++q) pout[q] *= rT;
    }
}

template<bool NORM, int VM, bool PF>
__device__ __forceinline__ void bstep(
    int i, int lane, int off,
    const float (&pin)[8], float (&pout)[8], float& c,
    Buf& B,
    const float* __restrict__ EeB, const float* __restrict__ WbB,
    float* __restrict__ pbB, float* ldsC)
{
    {
        f32x4 s0 = {pin[0], pin[1], pin[2], pin[3]};
        f32x4 s1 = {pin[4], pin[5], pin[6], pin[7]};
        astore2(s0, s1, pbB + (size_t)(i + 1) * JJ + off);   // pin holds row i+1
    }
    if (lane == 0) ldsC[i + 1] = c;
    waitcnt_vm<VM>();
    __builtin_amdgcn_sched_barrier(0);
    // reversed: CE[q] = rowdata[7-q]  (rowdata[k] = row[504-8*lane+k])
    float CE[8] = {B.e1[3],B.e1[2],B.e1[1],B.e1[0],B.e0[3],B.e0[2],B.e0[1],B.e0[0]};
    float CW[8] = {B.w1[3],B.w1[2],B.w1[1],B.w1[0],B.w0[3],B.w0[2],B.w0[1],B.w0[0]};
    if (PF) {
        aload2(B.e0, B.e1, EeB + (size_t)(i - 5) * JJ + 504 - 8 * lane);
        aload2(B.w0, B.w1, WbB + (size_t)(i - 5) * JJ + 504 - 8 * lane);
    }

    float pup = lane_shr1(pin[7]);
    float pn[8];
    pn[0] = pup;
    #pragma unroll
    for (int q = 1; q < 8; ++q) pn[q] = pin[q-1];
    float w[8];
    #pragma unroll
    for (int q = 0; q < 8; ++q) w[q] = pn[q] * CW[q];
    float W[8], N[8];
    tree_prefix8(w, W);
    tree_prefix8(pn, N);
    float sw = wscan_incl(W[7]);
    float sn = wscan_incl(N[7]);
    float ow = lane_shr1(sw);
    float on = lane_shr1(sn);
    float T  = bcast63(sn);
    #pragma unroll
    for (int q = 0; q < 8; ++q) {
        float QA = ow + W[q];                    // incl prefix of w
        float QB = fmaxf(T - (on + N[q]), 0.0f); // excl suffix of pn
        pout[q] = fmaf(CE[q], QA, K10 * QB);
    }
    if (NORM) {
        float Tc = fmaxf(T, 1e-30f);
        float rT = __builtin_amdgcn_rcpf(Tc);
        c += __logf(Tc);
        #pragma unroll
        for (int q = 0; q < 8; ++q) pout[q] *= rT;
    }
}

__global__ __launch_bounds__(64, 1) void scan_ab_kernel(
        const float* __restrict__ Ee, const float* __restrict__ Wa,
        const float* __restrict__ Wb,
        float* __restrict__ pa, float* __restrict__ pb,
        float* __restrict__ ca, float* __restrict__ cb) {
    __shared__ float ldsC[II];
    int b = blockIdx.x >> 1, dir = blockIdx.x & 1;
    int lane = threadIdx.x, off = lane * 8;
    size_t base = (size_t)b * II * JJ;
    float PS0[8],PS1[8],PS2[8],PS3[8],PS4[8],PS5[8],PS6[8],PS7[8],PS8[8],PS9[8];
    Buf B0,B1,B2,B3,B4;   // slot = row % 5
    float c = 0.0f;

    if (dir == 0) {
        const float* EeB = Ee + base; const float* WaB = Wa + base;
        float* paB = pa + base; float* caB = ca + b * II;
        // row 0 via compiler loads (their auto-wait lands before our asm stream)
        float e0r[8];
        loadrow8(EeB + off, e0r);
        float wa00 = WaB[0];
        #pragma unroll
        for (int q = 0; q < 8; ++q) PS0[q] = e0r[q] * wa00;   // row 0
        __builtin_amdgcn_sched_barrier(0);
        // asm prefetch rows 1..5 -> slots 1,2,3,4,0 (20 ops)
        aload2(B1.e0, B1.e1, EeB + (size_t)1*JJ + off); aload2(B1.w0, B1.w1, WaB + (size_t)1*JJ + off);
        aload2(B2.e0, B2.e1, EeB + (size_t)2*JJ + off); aload2(B2.w0, B2.w1, WaB + (size_t)2*JJ + off);
        aload2(B3.e0, B3.e1, EeB + (size_t)3*JJ + off); aload2(B3.w0, B3.w1, WaB + (size_t)3*JJ + off);
        aload2(B4.e0, B4.e1, EeB + (size_t)4*JJ + off); aload2(B4.w0, B4.w1, WaB + (size_t)4*JJ + off);
        aload2(B0.e0, B0.e1, EeB + (size_t)5*JJ + off); aload2(B0.w0, B0.w1, WaB + (size_t)5*JJ + off);
        // warm-up steps 1..5 (NORM at i%5==1)
        astep<true ,18,true>(1, lane, off, PS0, PS1, c, B1, EeB, WaB, paB, ldsC);
        astep<false,20,true>(2, lane, off, PS1, PS2, c, B2, EeB, WaB, paB, ldsC);
        astep<false,22,true>(3, lane, off, PS2, PS3, c, B3, EeB, WaB, paB, ldsC);
        astep<false,24,true>(4, lane, off, PS3, PS4, c, B4, EeB, WaB, paB, ldsC);
        astep<false,26,true>(5, lane, off, PS4, PS5, c, B0, EeB, WaB, paB, ldsC);
        #pragma unroll 1
        for (int d = 0; d < 11; ++d) {        // steps 6..115
            int i = 6 + 10 * d;
            astep<true ,26,true>(i+0, lane, off, PS5, PS6, c, B1, EeB, WaB, paB, ldsC);
            astep<false,26,true>(i+1, lane, off, PS6, PS7, c, B2, EeB, WaB, paB, ldsC);
            astep<false,26,true>(i+2, lane, off, PS7, PS8, c, B3, EeB, WaB, paB, ldsC);
            astep<false,26,true>(i+3, lane, off, PS8, PS9, c, B4, EeB, WaB, paB, ldsC);
            astep<false,26,true>(i+4, lane, off, PS9, PS0, c, B0, EeB, WaB, paB, ldsC);
            astep<true ,26,true>(i+5, lane, off, PS0, PS1, c, B1, EeB, WaB, paB, ldsC);
            astep<false,26,true>(i+6, lane, off, PS1, PS2, c, B2, EeB, WaB, paB, ldsC);
            astep<false,26,true>(i+7, lane, off, PS2, PS3, c, B3, EeB, WaB, paB, ldsC);
            astep<false,26,true>(i+8, lane, off, PS3, PS4, c, B4, EeB, WaB, paB, ldsC);
            astep<false,26,true>(i+9, lane, off, PS4, PS5, c, B0, EeB, WaB, paB, ldsC);
        }
        // steps 116..122 (PF continues: loads rows 121..127)
        astep<true ,26,true>(116, lane, off, PS5, PS6, c, B1, EeB, WaB, paB, ldsC);
        astep<false,26,true>(117, lane, off, PS6, PS7, c, B2, EeB, WaB, paB, ldsC);
        astep<false,26,true>(118, lane, off, PS7, PS8, c, B3, EeB, WaB, paB, ldsC);
        astep<false,26,true>(119, lane, off, PS8, PS9, c, B4, EeB, WaB, paB, ldsC);
        astep<false,26,true>(120, lane, off, PS9, PS0, c, B0, EeB, WaB, paB, ldsC);
        astep<true ,26,true>(121, lane, off, PS0, PS1, c, B1, EeB, WaB, paB, ldsC);
        astep<false,26,true>(122, lane, off, PS1, PS2, c, B2, EeB, WaB, paB, ldsC);
        // tail 123..127 (no PF), exact waits
        astep<false,26,false>(123, lane, off, PS2, PS3, c, B3, EeB, WaB, paB, ldsC);
        astep<false,22,false>(124, lane, off, PS3, PS4, c, B4, EeB, WaB, paB, ldsC);
        astep<false,18,false>(125, lane, off, PS4, PS5, c, B0, EeB, WaB, paB, ldsC);
        astep<true ,14,false>(126, lane, off, PS5, PS6, c, B1, EeB, WaB, paB, ldsC);
        astep<false,10,false>(127, lane, off, PS6, PS7, c, B2, EeB, WaB, paB, ldsC);
        storerow8(paB + (size_t)127 * JJ + off, PS7);
        if (lane == 0) ldsC[127] = c;
        waitcnt_vm<0>();                       // drain our asm stores before endpgm
        caB[lane]      = ldsC[lane];
        caB[lane + 64] = ldsC[lane + 64];
    } else {
        const float* EeB = Ee + base; const float* WbB = Wb + base;
        float* pbB = pb + base; float* cbB = cb + b * II;
        #pragma unroll
        for (int q = 0; q < 8; ++q) PS7[q] = 0.0f;
        PS7[0] = (lane == 0) ? 1.0f : 0.0f;   // row 127 (j'=0 <-> orig j=J-1)
        // asm prefetch rows 126..122 -> slots 1,0,4,3,2 (reversed addressing)
        aload2(B1.e0, B1.e1, EeB + (size_t)126*JJ + 504 - 8*lane); aload2(B1.w0, B1.w1, WbB + (size_t)126*JJ + 504 - 8*lane);
        aload2(B0.e0, B0.e1, EeB + (size_t)125*JJ + 504 - 8*lane); aload2(B0.w0, B0.w1, WbB + (size_t)125*JJ + 504 - 8*lane);
        aload2(B4.e0, B4.e1, EeB + (size_t)124*JJ + 504 - 8*lane); aload2(B4.w0, B4.w1, WbB + (size_t)124*JJ + 504 - 8*lane);
        aload2(B3.e0, B3.e1, EeB + (size_t)123*JJ + 504 - 8*lane); aload2(B3.w0, B3.w1, WbB + (size_t)123*JJ + 504 - 8*lane);
        aload2(B2.e0, B2.e1, EeB + (size_t)122*JJ + 504 - 8*lane); aload2(B2.w0, B2.w1, WbB + (size_t)122*JJ + 504 - 8*lane);
        // warm-up steps 126..122 (NORM at i%5==1)
        bstep<true ,18,true>(126, lane, off, PS7, PS6, c, B1, EeB, WbB, pbB, ldsC);
        bstep<false,20,true>(125, lane, off, PS6, PS5, c, B0, EeB, WbB, pbB, ldsC);
        bstep<false,22,true>(124, lane, off, PS5, PS4, c, B4, EeB, WbB, pbB, ldsC);
        bstep<false,24,true>(123, lane, off, PS4, PS3, c, B3, EeB, WbB, pbB, ldsC);
        bstep<false,26,true>(122, lane, off, PS3, PS2, c, B2, EeB, WbB, pbB, ldsC);
        #pragma unroll 1
        for (int d = 0; d < 11; ++d) {        // steps 121..12
            int i = 121 - 10 * d;
            bstep<true ,26,true>(i-0, lane, off, PS2, PS1, c, B1, EeB, WbB, pbB, ldsC);
            bstep<false,26,true>(i-1, lane, off, PS1, PS0, c, B0, EeB, WbB, pbB, ldsC);
            bstep<false,26,true>(i-2, lane, off, PS0, PS9, c, B4, EeB, WbB, pbB, ldsC);
            bstep<false,26,true>(i-3, lane, off, PS9, PS8, c, B3, EeB, WbB, pbB, ldsC);
            bstep<false,26,true>(i-4, lane, off, PS8, PS7, c, B2, EeB, WbB, pbB, ldsC);
            bstep<true ,26,true>(i-5, lane, off, PS7, PS6, c, B1, EeB, WbB, pbB, ldsC);
            bstep<false,26,true>(i-6, lane, off, PS6, PS5, c, B0, EeB, WbB, pbB, ldsC);
            bstep<false,26,true>(i-7, lane, off, PS5, PS4, c, B4, EeB, WbB, pbB, ldsC);
            bstep<false,26,true>(i-8, lane, off, PS4, PS3, c, B3, EeB, WbB, pbB, ldsC);
            bstep<false,26,true>(i-9, lane, off, PS3, PS2, c, B2, EeB, WbB, pbB, ldsC);
        }
        // steps 11..5 (PF continues: loads rows 6..0)
        bstep<true ,26,true>(11, lane, off, PS2, PS1, c, B1, EeB, WbB, pbB, ldsC);
        bstep<false,26,true>(10, lane, off, PS1, PS0, c, B0, EeB, WbB, pbB, ldsC);
        bstep<false,26,true>( 9, lane, off, PS0, PS9, c, B4, EeB, WbB, pbB, ldsC);
        bstep<false,26,true>( 8, lane, off, PS9, PS8, c, B3, EeB, WbB, pbB, ldsC);
        bstep<false,26,true>( 7, lane, off, PS8, PS7, c, B2, EeB, WbB, pbB, ldsC);
        bstep<true ,26,true>( 6, lane, off, PS7, PS6, c, B1, EeB, WbB, pbB, ldsC);
        bstep<false,26,true>( 5, lane, off, PS6, PS5, c, B0, EeB, WbB, pbB, ldsC);
        // tail 4..0 (no PF)
        bstep<false,26,false>(4, lane, off, PS5, PS4, c, B4, EeB, WbB, pbB, ldsC);
        bstep<false,22,false>(3, lane, off, PS4, PS3, c, B3, EeB, WbB, pbB, ldsC);
        bstep<false,18,false>(2, lane, off, PS3, PS2, c, B2, EeB, WbB, pbB, ldsC);
        bstep<true ,14,false>(1, lane, off, PS2, PS1, c, B1, EeB, WbB, pbB, ldsC);
        bstep<false,10,false>(0, lane, off, PS1, PS0, c, B0, EeB, WbB, pbB, ldsC);
        storerow8(pbB + off, PS0);          // row 0
        if (lane == 0) ldsC[0] = c;
        waitcnt_vm<0>();                    // drain our asm stores before endpgm
        cbB[lane]      = ldsC[lane];
        cbB[lane + 64] = ldsC[lane + 64];
    }
}

// ---------------- fused gamma + expand ----------------
__global__ __launch_bounds__(256) void gamma_expand_kernel(
        const float* __restrict__ pa, const float* __restrict__ pb,
        const float* __restrict__ ca, const float* __restrict__ cb,
        const float* __restrict__ text, const float* __restrict__ mmask,
        float* __restrict__ gamma_out, float* __restrict__ expanded) {
    __shared__ float wt[II][9];      // stride 9: phase-A writes ~2-way conflicts (free)
    __shared__ float Ei[II];
    __shared__ float red[8][33];     // partial column sums [q][ic]
    int b   = blockIdx.x >> 6;       // 64 tiles per batch
    int jj0 = (blockIdx.x & 63) * 8;
    int t = threadIdx.x;
    int q = t & 7, ic = t >> 3;      // ic 0..31 handles i = 4*ic..4*ic+3

    if (t < II) Ei[t] = ca[b*II + t] + cb[b*II + t];
    __syncthreads();
    float maxc = Ei[0];
    #pragma unroll 16
    for (int i = 1; i < II; ++i) maxc = fmaxf(maxc, Ei[i]);
    __syncthreads();
    if (t < II) Ei[t] = __expf(Ei[t] - maxc);
    __syncthreads();

    size_t idx0  = (size_t)b * II * JJ + jj0 + q;
    size_t idx0r = (size_t)b * II * JJ + (JJ - 1 - jj0 - q);   // pb stored j-reversed
    float d = 0.f;
    #pragma unroll
    for (int k = 0; k < 4; ++k) {
        int i = ic * 4 + k;
        float P = pa[idx0 + (size_t)i * JJ] * pb[idx0r + (size_t)i * JJ] * Ei[i];
        wt[i][q] = P;
        d += P;
    }
    red[q][ic] = d;
    __syncthreads();
    if (t < 8) {
        float s = 0.f;
        #pragma unroll
        for (int k = 0; k < 32; ++k) s += red[t][k];
        red[t][32] = 1.0f / fmaxf(s, 1e-37f);
    }
    __syncthreads();
    float rD = red[q][32];
    #pragma unroll
    for (int k = 0; k < 4; ++k) {
        int i = ic * 4 + k;
        float P = wt[i][q] * rD;
        wt[i][q] = P;
        gamma_out[idx0 + (size_t)i * JJ] = fmaxf(__logf(P), -1e30f);  // log(0)=-inf -> -1e30
    }
    __syncthreads();

    // phase B: expanded[b, jj0+qq, c=t] = mmask * sum_i wt[i][qq] * text[b,i,t]
    float acc[8] = {0,0,0,0,0,0,0,0};
    const float* txb = text + (size_t)b * II * CC + t;
    #pragma unroll 4
    for (int i = 0; i < II; ++i) {
        float tv = txb[(size_t)i * CC];
        #pragma unroll
        for (int qq = 0; qq < 8; ++qq) acc[qq] = fmaf(wt[i][qq], tv, acc[qq]);
    }
    #pragma unroll
    for (int qq = 0; qq < 8; ++qq) {
        expanded[(size_t)(b * JJ + jj0 + qq) * CC + t] =
            acc[qq] * mmask[b * JJ + jj0 + qq];
    }
}

extern "C" void kernel_launch(void* const* d_in, const int* in_sizes, int n_in,
                              void* d_out, int out_size, void* d_ws, size_t ws_size,
                              hipStream_t stream) {
    const float* text  = (const float*)d_in[0];
    const float* mel   = (const float*)d_in[1];
    const float* mmask = (const float*)d_in[3];
    const float* noise = (const float*)d_in[4];
    const float* ratio = (const float*)d_in[5];
    float* gamma_out = (float*)d_out;            // B*I*J floats
    float* expanded  = (float*)d_out + NEL;      // B*J*C floats

    float* ws = (float*)d_ws;
    float* Ee = ws;                  // NEL
    float* Wa = ws +   NEL;          // NEL
    float* Wb = ws + 2*NEL;          // NEL
    float* pa = ws + 3*NEL;          // NEL (aliased: e lives here pre-scan)
    float* pb = ws + 4*NEL;          // NEL (j-reversed layout)
    float* ca = ws + 5*NEL;          // BB*II
    float* cb = ws + 5*NEL + BB*II;  // BB*II
    float* e  = pa;                  // e dead once scan_ab starts writing pa

    hipLaunchKernelGGL(energy_kernel, dim3(BB, II/8, JJ/64), dim3(256), 0, stream,
                       text, mel, noise, ratio, e);
    hipLaunchKernelGGL(dscan_kernel, dim3(BB*II), dim3(64), 0, stream, e, Ee, Wa, Wb);
    hipLaunchKernelGGL(scan_ab_kernel, dim3(BB*2), dim3(64), 0, stream,
                       Ee, Wa, Wb, pa, pb, ca, cb);
    hipLaunchKernelGGL(gamma_expand_kernel, dim3(BB*64), dim3(256), 0, stream,
                       pa, pb, ca, cb, text, mmask, gamma_out, expanded);
}